// Round 1
// baseline (415.401 us; speedup 1.0000x reference)
//
#include <hip/hip_runtime.h>

#define NN 1024
#define FF 64
#define NBT 64

typedef float f32x4 __attribute__((ext_vector_type(4)));
typedef short s16x8 __attribute__((ext_vector_type(8)));

__device__ __forceinline__ short f2bf(float f) {
    unsigned u = __builtin_bit_cast(unsigned, f);
    u = (u + 0x7FFFu + ((u >> 16) & 1u)) >> 16;
    return (short)u;
}

// Kernel 1: Wh = h @ W (fp32 compute). Outputs:
//   WhT  bf16  [bt][c][j]   (transposed so k2 B-fragments are contiguous in j)
//   s1,s2 fp32 [bt][j]      (Wh . a1, Wh . a2)
// grid 512 = 64 batches x 4 row-groups? -> 8 groups of 128 rows; 256 thr: 2 thr/row (c-halves)
__global__ __launch_bounds__(256) void k1(const float* __restrict__ h,
                                          const float* __restrict__ W,
                                          const float* __restrict__ a,
                                          short* __restrict__ WhT,
                                          float* __restrict__ s1g,
                                          float* __restrict__ s2g) {
    __shared__ float Wl[64 * 64];   // [k][c]
    __shared__ float al[128];
    __shared__ float s1sh[128], s2sh[128];
    const int blk = blockIdx.x;
    const int bt = blk >> 3;
    const int rbase = (blk & 7) * 128;
    const int t = threadIdx.x;

    for (int i = t; i < 1024; i += 256)
        ((f32x4*)Wl)[i] = ((const f32x4*)W)[i];
    if (t < 32) ((f32x4*)al)[t] = ((const f32x4*)a)[t];
    __syncthreads();

    const int row = rbase + (t & 127);
    const int half = t >> 7;           // 0: c 0..31, 1: c 32..63
    const float* hrow = h + ((size_t)bt * NN + row) * FF;
    float hv[64];
#pragma unroll
    for (int i = 0; i < 16; i++)
        ((f32x4*)hv)[i] = ((const f32x4*)hrow)[i];

    float s1 = 0.f, s2 = 0.f;
    short* wt = WhT + (size_t)bt * FF * NN + row;
#pragma unroll
    for (int cgi = 0; cgi < 8; cgi++) {
        const int cg = half * 8 + cgi;       // float4 group of columns
        f32x4 acc = {0.f, 0.f, 0.f, 0.f};
#pragma unroll
        for (int k = 0; k < 64; k++) {
            f32x4 w4 = ((const f32x4*)Wl)[k * 16 + cg];  // broadcast read
            acc += hv[k] * w4;
        }
        const int c0 = cg * 4;
        s1 += acc.x * al[c0] + acc.y * al[c0 + 1] + acc.z * al[c0 + 2] + acc.w * al[c0 + 3];
        s2 += acc.x * al[64 + c0] + acc.y * al[64 + c0 + 1] + acc.z * al[64 + c0 + 2] + acc.w * al[64 + c0 + 3];
        wt[(size_t)(c0 + 0) * NN] = f2bf(acc.x);
        wt[(size_t)(c0 + 1) * NN] = f2bf(acc.y);
        wt[(size_t)(c0 + 2) * NN] = f2bf(acc.z);
        wt[(size_t)(c0 + 3) * NN] = f2bf(acc.w);
    }
    if (half == 1) { s1sh[t & 127] = s1; s2sh[t & 127] = s2; }
    __syncthreads();
    if (half == 0) {
        s1g[bt * NN + row] = s1 + s1sh[t];
        s2g[bt * NN + row] = s2 + s2sh[t];
    }
}

// Kernel 2: masked-softmax attention + P @ Wh via bf16 MFMA, + elu.
// grid 1024 = 64 batches x 16 row-tiles (64 rows). 256 threads = 4 waves.
// Staging role: thread t -> row r=t>>2 (of 64), j-chunk jc=(t&3)*8 within 32-wide tile.
// MFMA role: wave wv handles rows wv*16..+15; 4 c-groups of 16.
__global__ __launch_bounds__(256) void k2(const int* __restrict__ adj,
                                          const short* __restrict__ WhT,
                                          const float* __restrict__ s1g,
                                          const float* __restrict__ s2g,
                                          float* __restrict__ out) {
    __shared__ __align__(16) short Pa[64 * 40];   // P tile   [i][j], pad 32->40
    __shared__ __align__(16) short Pw[64 * 40];   // Wh tile  [c][j], pad 32->40
    __shared__ float s2l[NN];
    __shared__ float rsum[64];

    const int bx = blockIdx.x;
    const int bt = bx >> 4;
    const int ibase = (bx & 15) * 64;
    const int t = threadIdx.x;

    // stage the full s2 row for this batch (reused by all 32 j-tiles)
    ((f32x4*)s2l)[t] = ((const f32x4*)(s2g + bt * NN))[t];

    const int r = t >> 2;
    const int jc = (t & 3) * 8;
    const float s1v = s1g[bt * NN + ibase + r];
    float rs = 0.f;

    const int* adjp = adj + ((size_t)bt * NN + ibase + r) * NN + jc;
    const short* whp = WhT + (size_t)bt * FF * NN + (size_t)r * NN + jc;

    const int wv = t >> 6;
    const int l = t & 63;
    const int m = l & 15;
    const int q = l >> 4;
    const s16x8* aptr = (const s16x8*)&Pa[(wv * 16 + m) * 40 + q * 8];
    const s16x8* bp0 = (const s16x8*)&Pw[(0 * 16 + m) * 40 + q * 8];
    const s16x8* bp1 = (const s16x8*)&Pw[(1 * 16 + m) * 40 + q * 8];
    const s16x8* bp2 = (const s16x8*)&Pw[(2 * 16 + m) * 40 + q * 8];
    const s16x8* bp3 = (const s16x8*)&Pw[(3 * 16 + m) * 40 + q * 8];

    f32x4 acc0 = {0.f, 0.f, 0.f, 0.f};
    f32x4 acc1 = {0.f, 0.f, 0.f, 0.f};
    f32x4 acc2 = {0.f, 0.f, 0.f, 0.f};
    f32x4 acc3 = {0.f, 0.f, 0.f, 0.f};

    // prefetch tile 0
    int4 ca0 = *(const int4*)(adjp);
    int4 ca1 = *(const int4*)(adjp + 4);
    int4 cw  = *(const int4*)(whp);

    __syncthreads();   // s2l ready

    for (int jt = 0; jt < 32; jt++) {
        const int jn = (jt < 31) ? jt + 1 : 31;   // prefetch next tile (dup last: harmless)
        int4 na0 = *(const int4*)(adjp + jn * 32);
        int4 na1 = *(const int4*)(adjp + jn * 32 + 4);
        int4 nw  = *(const int4*)(whp + jn * 32);

        // compute P = adj ? exp(leaky(s1+s2)) : 0  (no max-subtraction needed: |e| small)
        int aj[8] = {ca0.x, ca0.y, ca0.z, ca0.w, ca1.x, ca1.y, ca1.z, ca1.w};
        f32x4 s2a = *(const f32x4*)&s2l[jt * 32 + jc];
        f32x4 s2b = *(const f32x4*)&s2l[jt * 32 + jc + 4];
        float sv[8] = {s2a.x, s2a.y, s2a.z, s2a.w, s2b.x, s2b.y, s2b.z, s2b.w};
        s16x8 pbv;
#pragma unroll
        for (int u = 0; u < 8; u++) {
            float e = s1v + sv[u];
            e = e > 0.f ? e : 0.2f * e;
            e = fminf(e, 60.f);                // paranoia clamp, never active in practice
            float p = (aj[u] > 0) ? __expf(e) : 0.f;
            rs += p;
            pbv[u] = f2bf(p);
        }
        *(s16x8*)&Pa[r * 40 + jc] = pbv;
        *(int4*)&Pw[r * 40 + jc] = cw;
        __syncthreads();

        s16x8 af = *aptr;
        acc0 = __builtin_amdgcn_mfma_f32_16x16x32_bf16(af, *bp0, acc0, 0, 0, 0);
        acc1 = __builtin_amdgcn_mfma_f32_16x16x32_bf16(af, *bp1, acc1, 0, 0, 0);
        acc2 = __builtin_amdgcn_mfma_f32_16x16x32_bf16(af, *bp2, acc2, 0, 0, 0);
        acc3 = __builtin_amdgcn_mfma_f32_16x16x32_bf16(af, *bp3, acc3, 0, 0, 0);
        __syncthreads();

        ca0 = na0; ca1 = na1; cw = nw;
    }

    // row-sum: 4 staging threads per row are consecutive lanes -> quad shuffle reduce
    rs += __shfl_xor(rs, 1);
    rs += __shfl_xor(rs, 2);
    if ((t & 3) == 0) rsum[r] = rs;
    __syncthreads();

    float rinv[4];
#pragma unroll
    for (int e = 0; e < 4; e++) {
        float rv = rsum[wv * 16 + q * 4 + e];
        rinv[e] = rv > 0.f ? 1.f / rv : 0.f;
    }
    float* outp = out + ((size_t)bt * NN + ibase + wv * 16 + q * 4) * FF + m;
#pragma unroll
    for (int e = 0; e < 4; e++) {
        float v0 = acc0[e] * rinv[e];
        float v1 = acc1[e] * rinv[e];
        float v2 = acc2[e] * rinv[e];
        float v3 = acc3[e] * rinv[e];
        v0 = v0 > 0.f ? v0 : expm1f(v0);
        v1 = v1 > 0.f ? v1 : expm1f(v1);
        v2 = v2 > 0.f ? v2 : expm1f(v2);
        v3 = v3 > 0.f ? v3 : expm1f(v3);
        float* o = outp + (size_t)e * FF;
        o[0]  = v0;
        o[16] = v1;
        o[32] = v2;
        o[48] = v3;
    }
}

extern "C" void kernel_launch(void* const* d_in, const int* in_sizes, int n_in,
                              void* d_out, int out_size, void* d_ws, size_t ws_size,
                              hipStream_t stream) {
    const float* h  = (const float*)d_in[0];
    const int*  adj = (const int*)d_in[1];
    const float* W  = (const float*)d_in[2];
    const float* a  = (const float*)d_in[3];
    float* out = (float*)d_out;

    short* WhT = (short*)d_ws;                                      // 64*64*1024*2 = 8 MB
    float* s1  = (float*)((char*)d_ws + (size_t)NBT * FF * NN * 2); // 256 KB
    float* s2  = s1 + NBT * NN;                                     // 256 KB

    k1<<<512, 256, 0, stream>>>(h, W, a, WhT, s1, s2);
    k2<<<1024, 256, 0, stream>>>(adj, WhT, s1, s2, out);
}